// Round 1
// baseline (250.130 us; speedup 1.0000x reference)
//
#include <hip/hip_runtime.h>

#define B_ROWS   16384
#define D_DIM    2048
#define L_LAYERS 6
#define THREADS  256
#define BLOCKS   1024   // 16 rows per block; W/b amortized across rows

// Each block: 256 threads, thread t owns 8 d-slots:
//   j=0..3 -> t*4 + j           (first 1024 elements of the row)
//   j=4..7 -> 1024 + t*4 + (j-4)
// Both float4 loads are perfectly coalesced (1 KiB per wave-instr quarter).
__global__ __launch_bounds__(THREADS) void cross_net_kernel(
    const float* __restrict__ x,
    const float* __restrict__ W,
    const float* __restrict__ b,
    float* __restrict__ out)
{
    const int t    = threadIdx.x;
    const int lane = t & 63;
    const int wid  = t >> 6;
    const int base0 = t * 4;
    const int base1 = 1024 + t * 4;

    __shared__ float s_part[4][L_LAYERS];

    // ---------- per-block setup: W -> regs, U = sum_i b_i, e[l] = (sum_{i<l} b_i) . W_l ----------
    float w[L_LAYERS][8];
    float prefix[8];
    float e_red[L_LAYERS];
    #pragma unroll
    for (int j = 0; j < 8; ++j) prefix[j] = 0.f;
    #pragma unroll
    for (int l = 0; l < L_LAYERS; ++l) e_red[l] = 0.f;

    #pragma unroll
    for (int l = 0; l < L_LAYERS; ++l) {
        const float4 w0 = *(const float4*)(W + l * D_DIM + base0);
        const float4 w1 = *(const float4*)(W + l * D_DIM + base1);
        w[l][0] = w0.x; w[l][1] = w0.y; w[l][2] = w0.z; w[l][3] = w0.w;
        w[l][4] = w1.x; w[l][5] = w1.y; w[l][6] = w1.z; w[l][7] = w1.w;
        const float4 b0 = *(const float4*)(b + l * D_DIM + base0);
        const float4 b1 = *(const float4*)(b + l * D_DIM + base1);
        const float bl[8] = {b0.x, b0.y, b0.z, b0.w, b1.x, b1.y, b1.z, b1.w};
        #pragma unroll
        for (int j = 0; j < 8; ++j) {
            e_red[l] += prefix[j] * w[l][j];  // uses prefix BEFORE adding b_l  => sum_{i<l}
            prefix[j] += bl[j];
        }
    }
    float U[8];
    #pragma unroll
    for (int j = 0; j < 8; ++j) U[j] = prefix[j];   // u_L = sum of all 6 b_i

    // block-reduce the 6 e partials
    #pragma unroll
    for (int l = 0; l < L_LAYERS; ++l) {
        float v = e_red[l];
        #pragma unroll
        for (int off = 32; off >= 1; off >>= 1) v += __shfl_xor(v, off, 64);
        e_red[l] = v;
    }
    if (lane == 0) {
        #pragma unroll
        for (int l = 0; l < L_LAYERS; ++l) s_part[wid][l] = e_red[l];
    }
    __syncthreads();
    float e[L_LAYERS];
    #pragma unroll
    for (int l = 0; l < L_LAYERS; ++l)
        e[l] = s_part[0][l] + s_part[1][l] + s_part[2][l] + s_part[3][l];
    __syncthreads();

    // ---------- row loop: out_row = c6 * x_row + U ----------
    const int rows_per_block = B_ROWS / BLOCKS;
    const int row0 = blockIdx.x * rows_per_block;
    for (int r = 0; r < rows_per_block; ++r) {
        const int row = row0 + r;
        const float* xr = x + (size_t)row * D_DIM;
        const float4 x0 = *(const float4*)(xr + base0);
        const float4 x1 = *(const float4*)(xr + base1);
        const float xv[8] = {x0.x, x0.y, x0.z, x0.w, x1.x, x1.y, x1.z, x1.w};

        // 6 independent partial dots d_l = x0 . W_l
        float p[L_LAYERS];
        #pragma unroll
        for (int l = 0; l < L_LAYERS; ++l) {
            float acc = 0.f;
            #pragma unroll
            for (int j = 0; j < 8; ++j) acc += xv[j] * w[l][j];
            p[l] = acc;
        }
        // wave butterfly reduce (6 independent chains -> ILP hides shuffle latency)
        #pragma unroll
        for (int l = 0; l < L_LAYERS; ++l) {
            #pragma unroll
            for (int off = 32; off >= 1; off >>= 1) p[l] += __shfl_xor(p[l], off, 64);
        }
        if (lane == 0) {
            #pragma unroll
            for (int l = 0; l < L_LAYERS; ++l) s_part[wid][l] = p[l];
        }
        __syncthreads();

        // scalar recurrence (computed uniformly in every thread)
        float c = 1.f;
        #pragma unroll
        for (int l = 0; l < L_LAYERS; ++l) {
            const float dsum = s_part[0][l] + s_part[1][l] + s_part[2][l] + s_part[3][l];
            c = c * (1.f + dsum) + e[l];
        }

        float* orow = out + (size_t)row * D_DIM;
        float4 o0, o1;
        o0.x = c * xv[0] + U[0]; o0.y = c * xv[1] + U[1];
        o0.z = c * xv[2] + U[2]; o0.w = c * xv[3] + U[3];
        o1.x = c * xv[4] + U[4]; o1.y = c * xv[5] + U[5];
        o1.z = c * xv[6] + U[6]; o1.w = c * xv[7] + U[7];
        *(float4*)(orow + base0) = o0;
        *(float4*)(orow + base1) = o1;

        __syncthreads();  // s_part reused next row
    }
}

extern "C" void kernel_launch(void* const* d_in, const int* in_sizes, int n_in,
                              void* d_out, int out_size, void* d_ws, size_t ws_size,
                              hipStream_t stream) {
    (void)in_sizes; (void)n_in; (void)d_ws; (void)ws_size; (void)out_size;
    const float* x = (const float*)d_in[0];
    const float* W = (const float*)d_in[1];
    const float* b = (const float*)d_in[2];
    float* out = (float*)d_out;
    cross_net_kernel<<<dim3(BLOCKS), dim3(THREADS), 0, stream>>>(x, W, b, out);
}